// Round 1
// baseline (344.329 us; speedup 1.0000x reference)
//
#include <hip/hip_runtime.h>
#include <stdint.h>

// MHA: B=4, S=2048, D=1024, H=16, HD=64.
// Pipeline: f32->bf16 cvt -> fused QKV GEMM (bf16 MFMA) -> flash attn (bf16 MFMA,
// fp32 online softmax) -> output GEMM (bf16 MFMA, fp32 out).
// Q is pre-scaled by 0.125*log2(e) so softmax uses exp2 directly (exact semantics).

typedef __bf16 bf16x8 __attribute__((ext_vector_type(8)));
typedef float f32x4 __attribute__((ext_vector_type(4)));

__device__ __forceinline__ uint16_t f2bf(float f) {
  union { float f; uint32_t u; } c;
  c.f = f;
  uint32_t u = c.u + 0x7fffu + ((c.u >> 16) & 1u);  // RNE
  return (uint16_t)(u >> 16);
}

__device__ __forceinline__ void gload16(const void* g, void* l) {
  __builtin_amdgcn_global_load_lds(
      (const __attribute__((address_space(1))) uint32_t*)g,
      (__attribute__((address_space(3))) uint32_t*)l,
      16, 0, 0);
}

__global__ void cvt_f32_bf16(const float* __restrict__ in,
                             uint16_t* __restrict__ out, int n4) {
  int i = blockIdx.x * blockDim.x + threadIdx.x;
  if (i >= n4) return;
  float4 v = reinterpret_cast<const float4*>(in)[i];
  union { uint16_t u[4]; uint2 d; } o;
  o.u[0] = f2bf(v.x); o.u[1] = f2bf(v.y);
  o.u[2] = f2bf(v.z); o.u[3] = f2bf(v.w);
  reinterpret_cast<uint2*>(out)[i] = o.d;
}

// C[m,n] = sum_k A[m,k] * W[n,k] + bias  (torch Linear). A,W bf16 row-major K=1024.
// MODE 0: QKV fused (N=3072, weight/bias selected per 1024-col group).
//   q -> oq[bh][s][hd] bf16, scaled by 0.125*log2e; k -> ok[bh][s][hd]; v -> ovT[bh][hd][s].
// MODE 1: out-proj (N=1024), writes fp32 ofp[m][n].
template <int MODE>
__global__ __launch_bounds__(256, 2)
void gemm_nt(const uint16_t* __restrict__ A,
             const uint16_t* __restrict__ W0, const uint16_t* __restrict__ W1,
             const uint16_t* __restrict__ W2,
             const float* __restrict__ b0, const float* __restrict__ b1,
             const float* __restrict__ b2,
             uint16_t* __restrict__ oq, uint16_t* __restrict__ ok2,
             uint16_t* __restrict__ ovT, float* __restrict__ ofp) {
  __shared__ __align__(16) uint16_t Alds[2][128 * 32];
  __shared__ __align__(16) uint16_t Blds[2][128 * 32];

  const int tid = threadIdx.x;
  const int w = tid >> 6;
  const int l = tid & 63;
  const int wm = w >> 1, wn = w & 1;
  const int g = l >> 4, c16 = l & 15;
  const int brow = blockIdx.y * 128;
  const int bcol = blockIdx.x * 128;

  const uint16_t* Wsel = W0;
  const float* bsel = b0;
  if (MODE == 0) {
    const int which = bcol >> 10;
    Wsel = (which == 0) ? W0 : ((which == 1) ? W1 : W2);
    bsel = (which == 0) ? b0 : ((which == 1) ? b1 : b2);
  }
  const int bw = bcol & 1023;

  const int srow = l >> 2;         // staging: row-within-16 (chunk c adds c*16)
  const int scol = (l & 3) * 8;    // staging: col (8 bf16 = 16B per lane)

  f32x4 acc[4][4];
#pragma unroll
  for (int i = 0; i < 4; ++i)
#pragma unroll
    for (int j = 0; j < 4; ++j) acc[i][j] = {0.f, 0.f, 0.f, 0.f};

  // prologue stage kt=0 into buf 0
#pragma unroll
  for (int i2 = 0; i2 < 2; ++i2) {
    const int c = 2 * w + i2;
    gload16(A + (size_t)(brow + c * 16 + srow) * 1024 + scol, &Alds[0][c * 512]);
    gload16(Wsel + (size_t)(bw + c * 16 + srow) * 1024 + scol, &Blds[0][c * 512]);
  }

  for (int kt = 0; kt < 32; ++kt) {
    __syncthreads();  // buf[kt&1] staged; all waves done reading buf[(kt+1)&1]
    const int cur = kt & 1;
    if (kt + 1 < 32) {
      const int k0 = (kt + 1) * 32;
#pragma unroll
      for (int i2 = 0; i2 < 2; ++i2) {
        const int c = 2 * w + i2;
        gload16(A + (size_t)(brow + c * 16 + srow) * 1024 + k0 + scol,
                &Alds[cur ^ 1][c * 512]);
        gload16(Wsel + (size_t)(bw + c * 16 + srow) * 1024 + k0 + scol,
                &Blds[cur ^ 1][c * 512]);
      }
    }
    bf16x8 af[4], bfr[4];
#pragma unroll
    for (int i = 0; i < 4; ++i)
      af[i] = *reinterpret_cast<const bf16x8*>(
          &Alds[cur][(wm * 64 + i * 16 + c16) * 32 + g * 8]);
#pragma unroll
    for (int j = 0; j < 4; ++j)
      bfr[j] = *reinterpret_cast<const bf16x8*>(
          &Blds[cur][(wn * 64 + j * 16 + c16) * 32 + g * 8]);
#pragma unroll
    for (int i = 0; i < 4; ++i)
#pragma unroll
      for (int j = 0; j < 4; ++j)
        acc[i][j] = __builtin_amdgcn_mfma_f32_16x16x32_bf16(af[i], bfr[j],
                                                            acc[i][j], 0, 0, 0);
  }

  // epilogue: D row = 4*(l>>4)+reg, col = l&15 (m89-verified)
#pragma unroll
  for (int i = 0; i < 4; ++i) {
#pragma unroll
    for (int j = 0; j < 4; ++j) {
      const int n = bcol + wn * 64 + j * 16 + c16;
      const int nn = n & 1023;
      const float bias = bsel[nn];
#pragma unroll
      for (int r = 0; r < 4; ++r) {
        const int m = brow + wm * 64 + i * 16 + g * 4 + r;
        const float val = acc[i][j][r] + bias;
        if (MODE == 0) {
          const int which = n >> 10;
          const int s = m & 2047, b = m >> 11;
          const int h = nn >> 6, hd = nn & 63;
          const size_t bh = (size_t)(b * 16 + h);
          if (which == 0)
            oq[(bh * 2048 + s) * 64 + hd] = f2bf(val * 0.18033688011112042f);
          else if (which == 1)
            ok2[(bh * 2048 + s) * 64 + hd] = f2bf(val);
          else
            ovT[(bh * 64 + hd) * 2048 + s] = f2bf(val);
        } else {
          ofp[(size_t)m * 1024 + n] = val;
        }
      }
    }
  }
}

// Flash attention. Grid (qb=32, bh=64), 256 threads = 4 waves, wave owns 16 q-rows.
// K tile [64 keys][64 hd], V^T tile [64 hd][64 keys] in LDS, XOR-swizzled
// (byte ^= (row&7)<<4) with inverse-swizzled global source (T21 both-sides rule).
__global__ __launch_bounds__(256, 2)
void attn_fwd(const uint16_t* __restrict__ Q, const uint16_t* __restrict__ K,
              const uint16_t* __restrict__ VT, uint16_t* __restrict__ CTX) {
  __shared__ __align__(16) uint16_t Klds[2][64 * 64];
  __shared__ __align__(16) uint16_t Vlds[2][64 * 64];
  __shared__ __align__(16) uint16_t Plds[4][16 * 72];  // stride 72: 16B-aligned rows, conflict-light

  const int tid = threadIdx.x;
  const int w = tid >> 6;
  const int l = tid & 63;
  const int g = l >> 4, c16 = l & 15;
  const int qb = blockIdx.x;
  const int bh = blockIdx.y;

  // Q fragments (row = l&15, k = 8*(l>>4)+j), hoisted for whole kernel
  const uint16_t* qptr =
      Q + ((size_t)bh * 2048 + qb * 64 + w * 16 + c16) * 64 + g * 8;
  const bf16x8 q0 = *reinterpret_cast<const bf16x8*>(qptr);
  const bf16x8 q1 = *reinterpret_cast<const bf16x8*>(qptr + 32);

  f32x4 ctx[4];
#pragma unroll
  for (int ht = 0; ht < 4; ++ht) ctx[ht] = {0.f, 0.f, 0.f, 0.f};
  float M[4], L[4];
#pragma unroll
  for (int r = 0; r < 4; ++r) { M[r] = -__builtin_inff(); L[r] = 0.f; }

  uint16_t* const myP = &Plds[w][0];

  auto stage = [&](int kt, int buf) {
#pragma unroll
    for (int i2 = 0; i2 < 2; ++i2) {
      const int c = 2 * w + i2;
      const int lb = c * 1024 + l * 16;          // linear dest byte in 8KB tile
      const int row = lb >> 7;                   // 128B rows
      const int so = lb ^ ((row & 7) << 4);      // inverse-swizzled source byte
      const int colel = (so & 127) >> 1;
      gload16(K + ((size_t)bh * 2048 + kt * 64 + row) * 64 + colel,
              &Klds[buf][c * 512]);
      gload16(VT + ((size_t)bh * 64 + row) * 2048 + kt * 64 + colel,
              &Vlds[buf][c * 512]);
    }
  };

  stage(0, 0);

  for (int kt = 0; kt < 32; ++kt) {
    __syncthreads();
    const int cur = kt & 1;
    if (kt + 1 < 32) stage(kt + 1, cur ^ 1);
    const uint8_t* kb = reinterpret_cast<const uint8_t*>(&Klds[cur][0]);
    const uint8_t* vb = reinterpret_cast<const uint8_t*>(&Vlds[cur][0]);

    // scores: 4 sub-tiles of 16 keys; B-frag from swizzled K tile
    f32x4 sc[4];
#pragma unroll
    for (int t = 0; t < 4; ++t) {
      const int key = t * 16 + c16;
      const int byt = key * 128 + g * 16;
      const int swz = (key & 7) << 4;
      const bf16x8 k0 = *reinterpret_cast<const bf16x8*>(kb + (byt ^ swz));
      const bf16x8 k1 = *reinterpret_cast<const bf16x8*>(kb + ((byt + 64) ^ swz));
      f32x4 s = {0.f, 0.f, 0.f, 0.f};
      s = __builtin_amdgcn_mfma_f32_16x16x32_bf16(q0, k0, s, 0, 0, 0);
      s = __builtin_amdgcn_mfma_f32_16x16x32_bf16(q1, k1, s, 0, 0, 0);
      sc[t] = s;
    }

    // online softmax (rows = 4*(l>>4)+r live across lanes c16 = key cols)
    float mloc[4];
#pragma unroll
    for (int r = 0; r < 4; ++r)
      mloc[r] = fmaxf(fmaxf(sc[0][r], sc[1][r]), fmaxf(sc[2][r], sc[3][r]));
#pragma unroll
    for (int off = 1; off <= 8; off <<= 1)
#pragma unroll
      for (int r = 0; r < 4; ++r)
        mloc[r] = fmaxf(mloc[r], __shfl_xor(mloc[r], off));

    float corr[4];
#pragma unroll
    for (int r = 0; r < 4; ++r) {
      const float mn = fmaxf(M[r], mloc[r]);
      corr[r] = exp2f(M[r] - mn);  // first iter: exp2(-inf)=0
      M[r] = mn;
      L[r] *= corr[r];
    }
#pragma unroll
    for (int ht = 0; ht < 4; ++ht)
#pragma unroll
      for (int r = 0; r < 4; ++r) ctx[ht][r] *= corr[r];

#pragma unroll
    for (int t = 0; t < 4; ++t)
#pragma unroll
      for (int r = 0; r < 4; ++r) {
        const float p = exp2f(sc[t][r] - M[r]);
        L[r] += p;  // lane-partial row sum; cross-lane reduced at end
        myP[(g * 4 + r) * 72 + t * 16 + c16] = f2bf(p);  // transpose via LDS
      }

    asm volatile("s_waitcnt lgkmcnt(0)" ::: "memory");  // wave-local P ready

    const bf16x8 pa0 = *reinterpret_cast<const bf16x8*>(&myP[c16 * 72 + g * 8]);
    const bf16x8 pa1 =
        *reinterpret_cast<const bf16x8*>(&myP[c16 * 72 + 32 + g * 8]);

#pragma unroll
    for (int ht = 0; ht < 4; ++ht) {
      const int hd = ht * 16 + c16;
      const int byt = hd * 128 + g * 16;
      const int swz = (hd & 7) << 4;
      const bf16x8 v0 = *reinterpret_cast<const bf16x8*>(vb + (byt ^ swz));
      const bf16x8 v1 = *reinterpret_cast<const bf16x8*>(vb + ((byt + 64) ^ swz));
      ctx[ht] = __builtin_amdgcn_mfma_f32_16x16x32_bf16(pa0, v0, ctx[ht], 0, 0, 0);
      ctx[ht] = __builtin_amdgcn_mfma_f32_16x16x32_bf16(pa1, v1, ctx[ht], 0, 0, 0);
    }
  }

  // finalize: full row-sums, divide, store token-major bf16 ctx
#pragma unroll
  for (int off = 1; off <= 8; off <<= 1)
#pragma unroll
    for (int r = 0; r < 4; ++r) L[r] += __shfl_xor(L[r], off);

  const int b = bh >> 4, h = bh & 15;
#pragma unroll
  for (int ht = 0; ht < 4; ++ht)
#pragma unroll
    for (int r = 0; r < 4; ++r) {
      const int s = qb * 64 + w * 16 + g * 4 + r;
      const int col = h * 64 + ht * 16 + c16;
      CTX[((size_t)b * 2048 + s) * 1024 + col] = f2bf(ctx[ht][r] / L[r]);
    }
}

extern "C" void kernel_launch(void* const* d_in, const int* in_sizes, int n_in,
                              void* d_out, int out_size, void* d_ws,
                              size_t ws_size, hipStream_t stream) {
  (void)in_sizes; (void)n_in; (void)out_size; (void)ws_size;
  const float* x = (const float*)d_in[0];
  const float* wq = (const float*)d_in[1];
  const float* bq = (const float*)d_in[2];
  const float* wk = (const float*)d_in[3];
  const float* bk = (const float*)d_in[4];
  const float* wv = (const float*)d_in[5];
  const float* bv = (const float*)d_in[6];
  const float* wo = (const float*)d_in[7];
  const float* bo = (const float*)d_in[8];
  float* out = (float*)d_out;

  // ws layout (88 MB total)
  uint8_t* ws = (uint8_t*)d_ws;
  uint16_t* xb   = (uint16_t*)(ws + 0);                       // 16 MB  x bf16 [8192][1024]
  uint16_t* wqb  = (uint16_t*)(ws + 16777216);                // 2 MB each
  uint16_t* wkb  = (uint16_t*)(ws + 16777216 + 2097152);
  uint16_t* wvb  = (uint16_t*)(ws + 16777216 + 2 * 2097152);
  uint16_t* wob  = (uint16_t*)(ws + 16777216 + 3 * 2097152);
  uint16_t* qws  = (uint16_t*)(ws + 25165824);                // 16 MB [bh][s][hd]
  uint16_t* kws  = (uint16_t*)(ws + 25165824 + 16777216);     // 16 MB [bh][s][hd]
  uint16_t* vtws = (uint16_t*)(ws + 25165824 + 2 * 16777216); // 16 MB [bh][hd][s]
  uint16_t* ctxw = (uint16_t*)(ws + 25165824 + 3 * 16777216); // 16 MB [b][s][1024]

  cvt_f32_bf16<<<8192, 256, 0, stream>>>(x, xb, 2097152);
  cvt_f32_bf16<<<1024, 256, 0, stream>>>(wq, wqb, 262144);
  cvt_f32_bf16<<<1024, 256, 0, stream>>>(wk, wkb, 262144);
  cvt_f32_bf16<<<1024, 256, 0, stream>>>(wv, wvb, 262144);
  cvt_f32_bf16<<<1024, 256, 0, stream>>>(wo, wob, 262144);

  gemm_nt<0><<<dim3(24, 64), 256, 0, stream>>>(
      xb, wqb, wkb, wvb, bq, bk, bv, qws, kws, vtws, nullptr);
  attn_fwd<<<dim3(32, 64), 256, 0, stream>>>(qws, kws, vtws, ctxw);
  gemm_nt<1><<<dim3(8, 64), 256, 0, stream>>>(
      ctxw, wob, nullptr, nullptr, bo, nullptr, nullptr, nullptr, nullptr,
      nullptr, out);
}

// Round 2
// 251.121 us; speedup vs baseline: 1.3712x; 1.3712x over previous
//
#include <hip/hip_runtime.h>
#include <stdint.h>

// MHA: B=4, S=2048, D=1024, H=16, HD=64.
// Pipeline: f32->bf16 cvt -> fused QKV GEMM (bf16 MFMA) -> flash attn (bf16 MFMA,
// fp32 online softmax, fully in-register P) -> output GEMM (bf16 MFMA, fp32 out).
// Q is pre-scaled by 0.125*log2(e) so softmax uses exp2 directly (exact semantics).

typedef __bf16 bf16x8 __attribute__((ext_vector_type(8)));
typedef float f32x4 __attribute__((ext_vector_type(4)));

__device__ __forceinline__ uint16_t f2bf(float f) {
  union { float f; uint32_t u; } c;
  c.f = f;
  uint32_t u = c.u + 0x7fffu + ((c.u >> 16) & 1u);  // RNE
  return (uint16_t)(u >> 16);
}

__device__ __forceinline__ float exp2_hw(float x) {
#if defined(__has_builtin) && __has_builtin(__builtin_amdgcn_exp2f)
  return __builtin_amdgcn_exp2f(x);
#else
  return exp2f(x);
#endif
}

__device__ __forceinline__ uint32_t cvt_pk_bf16(float lo, float hi) {
  uint32_t r;
  asm("v_cvt_pk_bf16_f32 %0, %1, %2" : "=v"(r) : "v"(lo), "v"(hi));
  return r;
}

__device__ __forceinline__ void gload16(const void* g, void* l) {
  __builtin_amdgcn_global_load_lds(
      (const __attribute__((address_space(1))) uint32_t*)g,
      (__attribute__((address_space(3))) uint32_t*)l,
      16, 0, 0);
}

__global__ void cvt_f32_bf16(const float* __restrict__ in,
                             uint16_t* __restrict__ out, int n4) {
  int i = blockIdx.x * blockDim.x + threadIdx.x;
  if (i >= n4) return;
  float4 v = reinterpret_cast<const float4*>(in)[i];
  union { uint16_t u[4]; uint2 d; } o;
  o.u[0] = f2bf(v.x); o.u[1] = f2bf(v.y);
  o.u[2] = f2bf(v.z); o.u[3] = f2bf(v.w);
  reinterpret_cast<uint2*>(out)[i] = o.d;
}

// C[m,n] = sum_k A[m,k] * W[n,k] + bias  (torch Linear). A,W bf16 row-major K=1024.
// MODE 0: QKV fused (N=3072, weight/bias selected per 1024-col group).
//   q -> oq[bh][s][hd] bf16, scaled by 0.125*log2e; k -> ok[bh][s][hd]; v -> ovT[bh][hd][s].
// MODE 1: out-proj (N=1024), writes fp32 ofp[m][n].
template <int MODE>
__global__ __launch_bounds__(256, 2)
void gemm_nt(const uint16_t* __restrict__ A,
             const uint16_t* __restrict__ W0, const uint16_t* __restrict__ W1,
             const uint16_t* __restrict__ W2,
             const float* __restrict__ b0, const float* __restrict__ b1,
             const float* __restrict__ b2,
             uint16_t* __restrict__ oq, uint16_t* __restrict__ ok2,
             uint16_t* __restrict__ ovT, float* __restrict__ ofp) {
  __shared__ __align__(16) uint16_t Alds[2][128 * 32];
  __shared__ __align__(16) uint16_t Blds[2][128 * 32];

  const int tid = threadIdx.x;
  const int w = tid >> 6;
  const int l = tid & 63;
  const int wm = w >> 1, wn = w & 1;
  const int g = l >> 4, c16 = l & 15;
  const int brow = blockIdx.y * 128;
  const int bcol = blockIdx.x * 128;

  const uint16_t* Wsel = W0;
  const float* bsel = b0;
  if (MODE == 0) {
    const int which = bcol >> 10;
    Wsel = (which == 0) ? W0 : ((which == 1) ? W1 : W2);
    bsel = (which == 0) ? b0 : ((which == 1) ? b1 : b2);
  }
  const int bw = bcol & 1023;

  const int srow = l >> 2;         // staging: row-within-16 (chunk c adds c*16)
  const int scol = (l & 3) * 8;    // staging: col (8 bf16 = 16B per lane)

  f32x4 acc[4][4];
#pragma unroll
  for (int i = 0; i < 4; ++i)
#pragma unroll
    for (int j = 0; j < 4; ++j) acc[i][j] = {0.f, 0.f, 0.f, 0.f};

  // prologue stage kt=0 into buf 0
#pragma unroll
  for (int i2 = 0; i2 < 2; ++i2) {
    const int c = 2 * w + i2;
    gload16(A + (size_t)(brow + c * 16 + srow) * 1024 + scol, &Alds[0][c * 512]);
    gload16(Wsel + (size_t)(bw + c * 16 + srow) * 1024 + scol, &Blds[0][c * 512]);
  }

  for (int kt = 0; kt < 32; ++kt) {
    __syncthreads();  // buf[kt&1] staged; all waves done reading buf[(kt+1)&1]
    const int cur = kt & 1;
    if (kt + 1 < 32) {
      const int k0 = (kt + 1) * 32;
#pragma unroll
      for (int i2 = 0; i2 < 2; ++i2) {
        const int c = 2 * w + i2;
        gload16(A + (size_t)(brow + c * 16 + srow) * 1024 + k0 + scol,
                &Alds[cur ^ 1][c * 512]);
        gload16(Wsel + (size_t)(bw + c * 16 + srow) * 1024 + k0 + scol,
                &Blds[cur ^ 1][c * 512]);
      }
    }
    bf16x8 af[4], bfr[4];
#pragma unroll
    for (int i = 0; i < 4; ++i)
      af[i] = *reinterpret_cast<const bf16x8*>(
          &Alds[cur][(wm * 64 + i * 16 + c16) * 32 + g * 8]);
#pragma unroll
    for (int j = 0; j < 4; ++j)
      bfr[j] = *reinterpret_cast<const bf16x8*>(
          &Blds[cur][(wn * 64 + j * 16 + c16) * 32 + g * 8]);
#pragma unroll
    for (int i = 0; i < 4; ++i)
#pragma unroll
      for (int j = 0; j < 4; ++j)
        acc[i][j] = __builtin_amdgcn_mfma_f32_16x16x32_bf16(af[i], bfr[j],
                                                            acc[i][j], 0, 0, 0);
  }

  // epilogue: D row = 4*(l>>4)+reg, col = l&15 (m89-verified)
#pragma unroll
  for (int i = 0; i < 4; ++i) {
#pragma unroll
    for (int j = 0; j < 4; ++j) {
      const int n = bcol + wn * 64 + j * 16 + c16;
      const int nn = n & 1023;
      const float bias = bsel[nn];
#pragma unroll
      for (int r = 0; r < 4; ++r) {
        const int m = brow + wm * 64 + i * 16 + g * 4 + r;
        const float val = acc[i][j][r] + bias;
        if (MODE == 0) {
          const int which = n >> 10;
          const int s = m & 2047, b = m >> 11;
          const int h = nn >> 6, hd = nn & 63;
          const size_t bh = (size_t)(b * 16 + h);
          if (which == 0)
            oq[(bh * 2048 + s) * 64 + hd] = f2bf(val * 0.18033688011112042f);
          else if (which == 1)
            ok2[(bh * 2048 + s) * 64 + hd] = f2bf(val);
          else
            ovT[(bh * 64 + hd) * 2048 + s] = f2bf(val);
        } else {
          ofp[(size_t)m * 1024 + n] = val;
        }
      }
    }
  }
}

// Flash attention, swapped-operand form. Grid (qb=32, bh=64), 4 waves, wave owns
// 16 q-rows; lane (g,c16) owns the WHOLE q-row c16 (M,L scalar per lane).
// QK^T computed as mfma(K,Q) with per-tile permuted K rows so that each lane's
// 16 P values are exactly its own PV B-fragment -> P stays in registers
// (8 cvt_pk, zero LDS round-trip). PV computed as mfma(V^T, P).
__global__ __launch_bounds__(256, 4)
void attn_fwd(const uint16_t* __restrict__ Q, const uint16_t* __restrict__ K,
              const uint16_t* __restrict__ VT, uint16_t* __restrict__ CTX) {
  __shared__ __align__(16) uint16_t Klds[2][64 * 64];
  __shared__ __align__(16) uint16_t Vlds[2][64 * 64];

  const int tid = threadIdx.x;
  const int w = tid >> 6;
  const int l = tid & 63;
  const int g = l >> 4, c16 = l & 15;
  const int qb = blockIdx.x;
  const int bh = blockIdx.y;

  // Q fragment (B operand: col=l&15=q-row, k = 8*(l>>4)+j), hoisted
  const uint16_t* qptr =
      Q + ((size_t)bh * 2048 + qb * 64 + w * 16 + c16) * 64 + g * 8;
  const bf16x8 q0 = *reinterpret_cast<const bf16x8*>(qptr);
  const bf16x8 q1 = *reinterpret_cast<const bf16x8*>(qptr + 32);

  f32x4 ctx[4];
#pragma unroll
  for (int ht = 0; ht < 4; ++ht) ctx[ht] = {0.f, 0.f, 0.f, 0.f};
  float M = -1024.0f;  // finite sentinel: first tile forces a rescale w/ corr=0
  float L = 0.f;

  auto stage = [&](int kt, int buf) {
#pragma unroll
    for (int i2 = 0; i2 < 2; ++i2) {
      const int c = 2 * w + i2;
      const int lb = c * 1024 + l * 16;          // linear dest byte in 8KB tile
      const int row = lb >> 7;                   // 128B rows
      const int so = lb ^ ((row & 7) << 4);      // inverse-swizzled source byte
      const int colel = (so & 127) >> 1;
      gload16(K + ((size_t)bh * 2048 + kt * 64 + row) * 64 + colel,
              &Klds[buf][c * 512]);
      gload16(VT + ((size_t)bh * 64 + row) * 2048 + kt * 64 + colel,
              &Vlds[buf][c * 512]);
    }
  };

  stage(0, 0);

  for (int kt = 0; kt < 32; ++kt) {
    __syncthreads();
    const int cur = kt & 1;
    if (kt + 1 < 32) stage(kt + 1, cur ^ 1);
    const uint8_t* kb = reinterpret_cast<const uint8_t*>(&Klds[cur][0]);
    const uint8_t* vb = reinterpret_cast<const uint8_t*>(&Vlds[cur][0]);

    // QK^T swapped: sc[t] row = key-local (4g+r), col = q-row (c16).
    // Tile t covers keys 32*(t>>1) + 8*g + 4*(t&1) + r  (A-row x -> key kappa(t,x)).
    // C-init = -M folds the running-max subtraction into the MFMA.
    const float negM = -M;
    const f32x4 minit = {negM, negM, negM, negM};
    f32x4 sc[4];
    __builtin_amdgcn_s_setprio(1);
#pragma unroll
    for (int t = 0; t < 4; ++t) {
      const int key = ((t >> 1) << 5) + ((c16 >> 2) << 3) + ((t & 1) << 2) +
                      (c16 & 3);
      const int byt = key * 128 + g * 16;
      const int swz = (key & 7) << 4;
      const bf16x8 k0 = *reinterpret_cast<const bf16x8*>(kb + (byt ^ swz));
      const bf16x8 k1 = *reinterpret_cast<const bf16x8*>(kb + ((byt + 64) ^ swz));
      f32x4 s = __builtin_amdgcn_mfma_f32_16x16x32_bf16(k0, q0, minit, 0, 0, 0);
      sc[t] = __builtin_amdgcn_mfma_f32_16x16x32_bf16(k1, q1, s, 0, 0, 0);
    }
    __builtin_amdgcn_s_setprio(0);

    // in-lane max over this lane's 16 keys, then across the 4 lanes of this q-row
    float mloc = fmaxf(fmaxf(sc[0][0], sc[0][1]), fmaxf(sc[0][2], sc[0][3]));
#pragma unroll
    for (int t = 1; t < 4; ++t)
      mloc = fmaxf(mloc,
                   fmaxf(fmaxf(sc[t][0], sc[t][1]), fmaxf(sc[t][2], sc[t][3])));
    mloc = fmaxf(mloc, __shfl_xor(mloc, 16));
    mloc = fmaxf(mloc, __shfl_xor(mloc, 32));

    float p4[4][4];
    if (__any(mloc > 8.0f)) {  // defer-max: rescale only on >2^8 growth
      const float delta = fmaxf(mloc, 0.0f);
      const float corr = exp2_hw(-delta);
      M += delta;
      L *= corr;
#pragma unroll
      for (int ht = 0; ht < 4; ++ht)
#pragma unroll
        for (int r = 0; r < 4; ++r) ctx[ht][r] *= corr;
#pragma unroll
      for (int t = 0; t < 4; ++t)
#pragma unroll
        for (int r = 0; r < 4; ++r) p4[t][r] = exp2_hw(sc[t][r] - delta);
    } else {
#pragma unroll
      for (int t = 0; t < 4; ++t)
#pragma unroll
        for (int r = 0; r < 4; ++r) p4[t][r] = exp2_hw(sc[t][r]);
    }

#pragma unroll
    for (int t = 0; t < 4; ++t)
      L += (p4[t][0] + p4[t][1]) + (p4[t][2] + p4[t][3]);

    // pack P into PV B-fragments entirely in-register (keys already lane-local)
    uint32_t pk[4][2];
#pragma unroll
    for (int t = 0; t < 4; ++t) {
      pk[t][0] = cvt_pk_bf16(p4[t][0], p4[t][1]);
      pk[t][1] = cvt_pk_bf16(p4[t][2], p4[t][3]);
    }
    union { uint32_t u[4]; bf16x8 v; } pa0, pa1;
    pa0.u[0] = pk[0][0]; pa0.u[1] = pk[0][1];
    pa0.u[2] = pk[1][0]; pa0.u[3] = pk[1][1];
    pa1.u[0] = pk[2][0]; pa1.u[1] = pk[2][1];
    pa1.u[2] = pk[3][0]; pa1.u[3] = pk[3][1];

    // PV swapped: ctx[ht] row = hd-local (4g+r), col = q-row (c16)
    __builtin_amdgcn_s_setprio(1);
#pragma unroll
    for (int ht = 0; ht < 4; ++ht) {
      const int hd = ht * 16 + c16;
      const int byt = hd * 128 + g * 16;
      const int swz = (hd & 7) << 4;
      const bf16x8 v0 = *reinterpret_cast<const bf16x8*>(vb + (byt ^ swz));
      const bf16x8 v1 = *reinterpret_cast<const bf16x8*>(vb + ((byt + 64) ^ swz));
      ctx[ht] = __builtin_amdgcn_mfma_f32_16x16x32_bf16(v0, pa0.v, ctx[ht], 0, 0, 0);
      ctx[ht] = __builtin_amdgcn_mfma_f32_16x16x32_bf16(v1, pa1.v, ctx[ht], 0, 0, 0);
    }
    __builtin_amdgcn_s_setprio(0);
  }

  // finalize: L reduce across the 4 lanes of this q-row, normalize, store 8B/lane
  L += __shfl_xor(L, 16);
  L += __shfl_xor(L, 32);
  const float inv = 1.0f / L;

  const int b = bh >> 4, h = bh & 15;
  const int s = qb * 64 + w * 16 + c16;
#pragma unroll
  for (int ht = 0; ht < 4; ++ht) {
    uint2 st;
    st.x = cvt_pk_bf16(ctx[ht][0] * inv, ctx[ht][1] * inv);
    st.y = cvt_pk_bf16(ctx[ht][2] * inv, ctx[ht][3] * inv);
    *reinterpret_cast<uint2*>(
        &CTX[((size_t)b * 2048 + s) * 1024 + h * 64 + ht * 16 + 4 * g]) = st;
  }
}

extern "C" void kernel_launch(void* const* d_in, const int* in_sizes, int n_in,
                              void* d_out, int out_size, void* d_ws,
                              size_t ws_size, hipStream_t stream) {
  (void)in_sizes; (void)n_in; (void)out_size; (void)ws_size;
  const float* x = (const float*)d_in[0];
  const float* wq = (const float*)d_in[1];
  const float* bq = (const float*)d_in[2];
  const float* wk = (const float*)d_in[3];
  const float* bk = (const float*)d_in[4];
  const float* wv = (const float*)d_in[5];
  const float* bv = (const float*)d_in[6];
  const float* wo = (const float*)d_in[7];
  const float* bo = (const float*)d_in[8];
  float* out = (float*)d_out;

  // ws layout (88 MB total)
  uint8_t* ws = (uint8_t*)d_ws;
  uint16_t* xb   = (uint16_t*)(ws + 0);                       // 16 MB  x bf16 [8192][1024]
  uint16_t* wqb  = (uint16_t*)(ws + 16777216);                // 2 MB each
  uint16_t* wkb  = (uint16_t*)(ws + 16777216 + 2097152);
  uint16_t* wvb  = (uint16_t*)(ws + 16777216 + 2 * 2097152);
  uint16_t* wob  = (uint16_t*)(ws + 16777216 + 3 * 2097152);
  uint16_t* qws  = (uint16_t*)(ws + 25165824);                // 16 MB [bh][s][hd]
  uint16_t* kws  = (uint16_t*)(ws + 25165824 + 16777216);     // 16 MB [bh][s][hd]
  uint16_t* vtws = (uint16_t*)(ws + 25165824 + 2 * 16777216); // 16 MB [bh][hd][s]
  uint16_t* ctxw = (uint16_t*)(ws + 25165824 + 3 * 16777216); // 16 MB [b][s][1024]

  cvt_f32_bf16<<<8192, 256, 0, stream>>>(x, xb, 2097152);
  cvt_f32_bf16<<<1024, 256, 0, stream>>>(wq, wqb, 262144);
  cvt_f32_bf16<<<1024, 256, 0, stream>>>(wk, wkb, 262144);
  cvt_f32_bf16<<<1024, 256, 0, stream>>>(wv, wvb, 262144);
  cvt_f32_bf16<<<1024, 256, 0, stream>>>(wo, wob, 262144);

  gemm_nt<0><<<dim3(24, 64), 256, 0, stream>>>(
      xb, wqb, wkb, wvb, bq, bk, bv, qws, kws, vtws, nullptr);
  attn_fwd<<<dim3(32, 64), 256, 0, stream>>>(qws, kws, vtws, ctxw);
  gemm_nt<1><<<dim3(8, 64), 256, 0, stream>>>(
      ctxw, wob, nullptr, nullptr, bo, nullptr, nullptr, nullptr, nullptr,
      nullptr, out);
}